// Round 1
// baseline (714.375 us; speedup 1.0000x reference)
//
#include <hip/hip_runtime.h>
#include <hip/hip_bf16.h>

// Problem constants (static per reference)
#define NTOK 16384   // B*T
#define HD   512     // H
#define ED   8       // E experts
#define FD   2048    // F
#define CAP  5120    // capacity per expert
#define NA   32768   // NTOK * K(=2)

typedef __bf16 bf16x8 __attribute__((ext_vector_type(8)));
typedef float  f32x4  __attribute__((ext_vector_type(4)));

// Workspace layout (bytes). Total ~249 MB.
static constexpr size_t OFF_EIDX = 0;                                  // int[NA]
static constexpr size_t OFF_WGT  = 131072;                             // float[NA]
static constexpr size_t OFF_STOK = 262144;                             // int[ED*CAP]
static constexpr size_t OFF_ASLOT= 425984;                             // int[NA] (slot per assignment, -1 dropped)
static constexpr size_t OFF_W2T  = 1u << 20;                           // bf16[ED][HD][FD]
static constexpr size_t OFF_H    = OFF_W2T + (size_t)ED*HD*FD*2;       // bf16[ED][CAP][FD]
static constexpr size_t OFF_W1T  = OFF_H   + (size_t)ED*CAP*FD*2;      // bf16[ED][FD][HD]
static constexpr size_t OFF_XBF  = OFF_W1T + (size_t)ED*FD*HD*2;       // bf16[NTOK][HD]
static constexpr size_t OFF_EOUT = OFF_XBF + (size_t)NTOK*HD*2;        // fp16[ED][CAP][HD]

__device__ __forceinline__ unsigned short f2bf(float f) {
    __bf16 b = (__bf16)f;
    return __builtin_bit_cast(unsigned short, b);
}
__device__ __forceinline__ unsigned short f2h(float f) {
    _Float16 h = (_Float16)f;
    return __builtin_bit_cast(unsigned short, h);
}
__device__ __forceinline__ float h2f(unsigned short u) {
    return (float)__builtin_bit_cast(_Float16, u);
}

// gelu(tanh approx) == v * sigmoid(2*0.79788456*(v + 0.044715 v^3))  (exact identity)
__device__ __forceinline__ float gelu_fast(float v) {
    const float u = 1.5957691216057308f * (v + 0.044715f * v * v * v);
    return v / (1.f + __expf(-u));
}

// Direct global->LDS DMA, 16B per lane. LDS dest is wave-uniform base +
// lane*16 (HW semantics, m104/m108); global src is per-lane.
__device__ __forceinline__ void gl16(const unsigned short* g, unsigned short* l) {
    __builtin_amdgcn_global_load_lds(
        (const __attribute__((address_space(1))) unsigned int*)(const void*)g,
        (__attribute__((address_space(3))) unsigned int*)(void*)l, 16, 0, 0);
}

// ---------------------------------------------------------------------------
// in: [R][C] fp32 (per expert)  ->  out: [C][R] bf16 (per expert)
// ---------------------------------------------------------------------------
__global__ __launch_bounds__(256) void transpose_cast_kernel(
    const float* __restrict__ in, unsigned short* __restrict__ out, int R, int C)
{
    __shared__ unsigned short tile[32][33];
    const int e = blockIdx.z;
    in  += (size_t)e * R * C;
    out += (size_t)e * R * C;
    const int r0 = blockIdx.y * 32, c0 = blockIdx.x * 32;
    const int tr = threadIdx.x >> 3, tc = (threadIdx.x & 7) * 4;
    const float4 v = *(const float4*)(in + (size_t)(r0 + tr) * C + c0 + tc);
    tile[tr][tc + 0] = f2bf(v.x);
    tile[tr][tc + 1] = f2bf(v.y);
    tile[tr][tc + 2] = f2bf(v.z);
    tile[tr][tc + 3] = f2bf(v.w);
    __syncthreads();
    ushort4 o;
    o.x = tile[tc + 0][tr]; o.y = tile[tc + 1][tr];
    o.z = tile[tc + 2][tr]; o.w = tile[tc + 3][tr];
    *(ushort4*)(out + (size_t)(c0 + tr) * R + r0 + tc) = o;
}

// ---------------------------------------------------------------------------
// Router (+ fused x->bf16 cast): logits = x @ router_w (fp32), top-2, softmax.
// ---------------------------------------------------------------------------
__global__ __launch_bounds__(256) void router_kernel(
    const float* __restrict__ x, const float* __restrict__ rw,
    int* __restrict__ eidx, float* __restrict__ wgt,
    unsigned short* __restrict__ xbf)
{
    __shared__ float rws[HD * ED];
    const int tid = threadIdx.x;
    for (int i = tid * 4; i < HD * ED; i += 256 * 4)
        *(float4*)(rws + i) = *(const float4*)(rw + i);
    __syncthreads();

    const int wid = tid >> 6, lane = tid & 63;
    const int t = blockIdx.x * 4 + wid;
    const float* xr = x + (size_t)t * HD;

    float acc[ED];
#pragma unroll
    for (int e = 0; e < ED; e++) acc[e] = 0.f;

    float4 xv0 = *(const float4*)(xr + lane * 8);
    float4 xv1 = *(const float4*)(xr + lane * 8 + 4);
    float xv[8] = {xv0.x, xv0.y, xv0.z, xv0.w, xv1.x, xv1.y, xv1.z, xv1.w};

    union { unsigned short us[8]; uint4 v; } pk;
#pragma unroll
    for (int j = 0; j < 8; j++) pk.us[j] = f2bf(xv[j]);
    *(uint4*)(xbf + (size_t)t * HD + lane * 8) = pk.v;

#pragma unroll
    for (int j = 0; j < 8; j++) {
        const int h = lane * 8 + j;
#pragma unroll
        for (int e = 0; e < ED; e++) acc[e] += xv[j] * rws[h * ED + e];
    }
#pragma unroll
    for (int off = 32; off >= 1; off >>= 1) {
#pragma unroll
        for (int e = 0; e < ED; e++) acc[e] += __shfl_down(acc[e], off);
    }
    if (lane == 0) {
        int e0 = 0; float l0 = acc[0];
        for (int e = 1; e < ED; e++) if (acc[e] > l0) { l0 = acc[e]; e0 = e; }
        int e1 = 0; float l1 = -1e30f;
        for (int e = 0; e < ED; e++) {
            if (e == e0) continue;
            if (acc[e] > l1) { l1 = acc[e]; e1 = e; }
        }
        const float ex = expf(l1 - l0);
        const float inv = 1.f / (1.f + ex);
        eidx[t * 2 + 0] = e0;  eidx[t * 2 + 1] = e1;
        wgt [t * 2 + 0] = inv; wgt [t * 2 + 1] = ex * inv;
    }
}

// ---------------------------------------------------------------------------
// Deterministic slot assignment (stable-sort-by-expert semantics).
// Emits stok (slot -> token, for GEMM1 gather) and aslot (assignment -> slot,
// for the combine kernel; -1 = dropped).
// ---------------------------------------------------------------------------
__global__ __launch_bounds__(1024) void scan_kernel(
    const int* __restrict__ eidx,
    int* __restrict__ stok, int* __restrict__ aslot)
{
    __shared__ int running[ED];
    __shared__ int wcnt[16][ED];
    const int tid = threadIdx.x;

    for (int i = tid; i < ED * CAP; i += 1024) stok[i] = -1;
    if (tid < ED) running[tid] = 0;
    __syncthreads();

    const int lane = tid & 63, wid = tid >> 6;
    const unsigned long long below = (1ull << lane) - 1ull;

    for (int c = 0; c < NA / 1024; c++) {
        const int a = c * 1024 + tid;
        const int e = eidx[a];
        int myrank = 0;
#pragma unroll
        for (int ee = 0; ee < ED; ee++) {
            unsigned long long m = __ballot(e == ee);
            if (ee == e) myrank = __popcll(m & below);
            if (lane == 0) wcnt[wid][ee] = __popcll(m);
        }
        __syncthreads();
        int woff = 0;
        for (int ww = 0; ww < wid; ww++) woff += wcnt[ww][e];
        const int slot = running[e] + woff + myrank;
        if (slot < CAP) {
            stok[e * CAP + slot] = a >> 1;   // token = a / K
            aslot[a] = slot;
        } else {
            aslot[a] = -1;                   // dropped
        }
        __syncthreads();
        if (tid < ED) {
            int tot = 0;
            for (int ww = 0; ww < 16; ww++) tot += wcnt[ww][tid];
            running[tid] += tot;
        }
        __syncthreads();
    }
}

// ---------------------------------------------------------------------------
// MFMA GEMM, m97-structure: global_load_lds DMA staging (no VGPR round-trip,
// no ds_write port pressure), linear [2][128][32] LDS per operand (32 KB ->
// 5 blocks/CU), ONE barrier per K-step, 2-step-unrolled so buffer indices
// are compile-time.
// Bank-conflict fix: source-side XOR swizzle (m173 pattern) — LDS chunk c of
// row R holds global chunk c ^ ((R>>1)&3); fragment reads apply the same XOR.
// Read conflicts drop to 2-way (free, m136); DMA writes are linear (0-way).
// Mapping: id%8 == expert == XCD; n fastest so gathered A rows land in L2
// once and get reused by all n-tiles; expert weight slab L2-resident.
// G1=true : hout = gelu(gather(x) @ B + bias)  [bf16]
// G1=false: hout = A @ B + bias                [fp16] (combined later)
// ---------------------------------------------------------------------------
template<int KD, int ND, int NT, bool G1>
__global__ __launch_bounds__(256, 5) void gemm_mfma(
    const unsigned short* __restrict__ Abase,
    const unsigned short* __restrict__ Bt,
    const float* __restrict__ bias,
    const int* __restrict__ stok,
    unsigned short* __restrict__ hout)
{
    constexpr int BUFE = 128 * 32;            // 4096 elems = 8 KB per buf
    __shared__ __align__(16) unsigned short As[2 * BUFE];
    __shared__ __align__(16) unsigned short Bs[2 * BUFE];

    const int tid = threadIdx.x;
    const int e  = blockIdx.x & 7;            // expert == XCD (id%8 round-robin)
    const int g  = blockIdx.x >> 3;
    const int n0 = (g % NT) * 128;            // n fastest: reuse gathered A in L2
    const int m0 = (g / NT) * 128;

    const int lane = tid & 63;
    const int wid  = tid >> 6;

    // Staging map: wave w, instr p covers rows [(2w+p)*16, +16); lane ->
    // (row sub = lane>>2, chunk = lane&3). Global source chunk is XOR-swizzled.
    const int rsub = lane >> 2;                       // 0..15
    const int csw  = (lane & 3) ^ ((rsub >> 1) & 3);  // pre-swizzled src chunk

    const unsigned short *ag0, *ag1, *bg0, *bg1;
    {
        const int R0 = (wid * 2 + 0) * 16 + rsub;
        const int R1 = (wid * 2 + 1) * 16 + rsub;
        size_t a0, a1;
        if constexpr (G1) {
            const int t0 = stok[e * CAP + m0 + R0];
            const int t1 = stok[e * CAP + m0 + R1];
            a0 = (size_t)(t0 >= 0 ? t0 : 0);   // dropped -> row 0 (never read back)
            a1 = (size_t)(t1 >= 0 ? t1 : 0);
        } else {
            a0 = (size_t)(e * CAP + m0 + R0);
            a1 = (size_t)(e * CAP + m0 + R1);
        }
        ag0 = Abase + a0 * KD + csw * 8;
        ag1 = Abase + a1 * KD + csw * 8;
        bg0 = Bt + ((size_t)e * ND + n0 + R0) * KD + csw * 8;
        bg1 = Bt + ((size_t)e * ND + n0 + R1) * KD + csw * 8;
    }
    unsigned short* lA = As + (wid * 2) * 512;  // wave-uniform DMA dest bases
    unsigned short* lB = Bs + (wid * 2) * 512;

    const int wrow = (wid & 1) * 64;
    const int wcol = (wid >> 1) * 64;
    const int l15  = lane & 15;
    const int quad = lane >> 4;
    const int xq   = quad ^ ((l15 >> 1) & 3);   // read-side XOR (row>>1 & 3 == l15>>1 & 3)
    const int fA   = (wrow + l15) * 32 + xq * 8;
    const int fB   = (wcol + l15) * 32 + xq * 8;

    f32x4 acc[4][4];
#pragma unroll
    for (int i = 0; i < 4; i++)
#pragma unroll
        for (int j = 0; j < 4; j++) acc[i][j] = (f32x4)0.f;

#define STAGE(B, KC)                                                           \
    {                                                                          \
        gl16(ag0 + (KC), lA + (B) * BUFE);                                     \
        gl16(ag1 + (KC), lA + (B) * BUFE + 512);                               \
        gl16(bg0 + (KC), lB + (B) * BUFE);                                     \
        gl16(bg1 + (KC), lB + (B) * BUFE + 512);                               \
    }

#define COMPUTE(B)                                                             \
    {                                                                          \
        const unsigned short* Ab = As + (B) * BUFE;                            \
        const unsigned short* Bb = Bs + (B) * BUFE;                            \
        bf16x8 af[4], bfv[4];                                                  \
        _Pragma("unroll")                                                      \
        for (int i = 0; i < 4; i++) af[i]  = *(const bf16x8*)(Ab + fA + i * 512); \
        _Pragma("unroll")                                                      \
        for (int j = 0; j < 4; j++) bfv[j] = *(const bf16x8*)(Bb + fB + j * 512); \
        _Pragma("unroll")                                                      \
        for (int i = 0; i < 4; i++)                                            \
            _Pragma("unroll")                                                  \
            for (int j = 0; j < 4; j++)                                        \
                acc[i][j] = __builtin_amdgcn_mfma_f32_16x16x32_bf16(           \
                    af[i], bfv[j], acc[i][j], 0, 0, 0);                        \
    }

    // Prologue: DMA tile 0 into buf0; barrier drains vmcnt -> buf0 ready.
    STAGE(0, 0);
    __syncthreads();

    // Steady state: issue next tile's DMA first (hides under MFMA), compute
    // current, then one barrier (compiler emits the vmcnt/lgkm drain there).
    for (int kc = 0; kc <= KD - 128; kc += 64) {
        STAGE(1, kc + 32);
        COMPUTE(0);
        __syncthreads();
        STAGE(0, kc + 64);
        COMPUTE(1);
        __syncthreads();
    }
    STAGE(1, KD - 32);
    COMPUTE(0);
    __syncthreads();
    COMPUTE(1);
#undef STAGE
#undef COMPUTE

    // Epilogue. C/D layout: col = lane&15, row = quad*4 + reg.
#pragma unroll
    for (int i = 0; i < 4; i++) {
#pragma unroll
        for (int g2 = 0; g2 < 4; g2++) {
            const int m = wrow + i * 16 + quad * 4 + g2;
            unsigned short* hrow = hout + ((size_t)e * CAP + m0 + m) * ND + n0;
#pragma unroll
            for (int j = 0; j < 4; j++) {
                const int n = wcol + j * 16 + l15;
                const float v = acc[i][j][g2] + bias[(size_t)e * ND + n0 + n];
                hrow[n] = G1 ? f2bf(gelu_fast(v)) : f2h(v);
            }
        }
    }
}

// ---------------------------------------------------------------------------
// Combine: out[t] = sum_k wgt[t,k] * eout[eidx[t,k], aslot[t,k]]  (no atomics,
// fully coalesced; writes every output element so no memset needed).
// ---------------------------------------------------------------------------
__global__ __launch_bounds__(256) void combine_kernel(
    const unsigned short* __restrict__ eout,
    const int* __restrict__ eidx, const int* __restrict__ aslot,
    const float* __restrict__ wgt, float* __restrict__ out)
{
    const int tid = threadIdx.x;
    const int t  = blockIdx.x * 2 + (tid >> 7);   // 128 threads per token
    const int h0 = (tid & 127) * 4;
    float r0 = 0.f, r1 = 0.f, r2 = 0.f, r3 = 0.f;
#pragma unroll
    for (int k = 0; k < 2; k++) {
        const int a = t * 2 + k;
        const int s = aslot[a];
        if (s >= 0) {
            const float w = wgt[a];
            const int e = eidx[a];
            const ushort4 v = *(const ushort4*)(eout + ((size_t)e * CAP + s) * HD + h0);
            r0 += w * h2f(v.x); r1 += w * h2f(v.y);
            r2 += w * h2f(v.z); r3 += w * h2f(v.w);
        }
    }
    float4 o; o.x = r0; o.y = r1; o.z = r2; o.w = r3;
    *(float4*)(out + (size_t)t * HD + h0) = o;
}

extern "C" void kernel_launch(void* const* d_in, const int* in_sizes, int n_in,
                              void* d_out, int out_size, void* d_ws, size_t ws_size,
                              hipStream_t stream)
{
    const float* x  = (const float*)d_in[0];
    const float* rw = (const float*)d_in[1];
    const float* w1 = (const float*)d_in[2];
    const float* b1 = (const float*)d_in[3];
    const float* w2 = (const float*)d_in[4];
    const float* b2 = (const float*)d_in[5];
    float* out = (float*)d_out;

    char* ws = (char*)d_ws;
    int*   eidx  = (int*)  (ws + OFF_EIDX);
    float* wgt   = (float*)(ws + OFF_WGT);
    int*   stok  = (int*)  (ws + OFF_STOK);
    int*   aslot = (int*)  (ws + OFF_ASLOT);
    unsigned short* w2t  = (unsigned short*)(ws + OFF_W2T);
    unsigned short* hbuf = (unsigned short*)(ws + OFF_H);
    unsigned short* w1t  = (unsigned short*)(ws + OFF_W1T);
    unsigned short* xbf  = (unsigned short*)(ws + OFF_XBF);
    unsigned short* eout = (unsigned short*)(ws + OFF_EOUT);

    transpose_cast_kernel<<<dim3(FD / 32, HD / 32, ED), 256, 0, stream>>>(w1, w1t, HD, FD);
    transpose_cast_kernel<<<dim3(HD / 32, FD / 32, ED), 256, 0, stream>>>(w2, w2t, FD, HD);
    router_kernel<<<NTOK / 4, 256, 0, stream>>>(x, rw, eidx, wgt, xbf);
    scan_kernel<<<1, 1024, 0, stream>>>(eidx, stok, aslot);

    // GEMM1: h = gelu(gather(x) @ w1 + b1)  [bf16]
    gemm_mfma<HD, FD, FD/128, true>
        <<<8 * (FD/128) * (CAP/128), 256, 0, stream>>>(
        xbf, w1t, b1, stok, hbuf);

    // GEMM2: eout = h @ w2 + b2  [fp16, per-slot]
    gemm_mfma<FD, HD, HD/128, false>
        <<<8 * (HD/128) * (CAP/128), 256, 0, stream>>>(
        hbuf, w2t, b2, nullptr, eout);

    // Weighted scatter-free combine (writes all tokens; replaces memset+atomics)
    combine_kernel<<<NTOK / 2, 256, 0, stream>>>(eout, eidx, aslot, wgt, out);
}

// Round 2
// 526.470 us; speedup vs baseline: 1.3569x; 1.3569x over previous
//
#include <hip/hip_runtime.h>
#include <hip/hip_bf16.h>

// Problem constants (static per reference)
#define NTOK 16384   // B*T
#define HD   512     // H
#define ED   8       // E experts
#define FD   2048    // F
#define CAP  5120    // capacity per expert
#define NA   32768   // NTOK * K(=2)

typedef __bf16 bf16x8 __attribute__((ext_vector_type(8)));
typedef float  f32x4  __attribute__((ext_vector_type(4)));

// Workspace layout (bytes). Total ~249 MB.
static constexpr size_t OFF_EIDX = 0;                                  // int[NA]
static constexpr size_t OFF_WGT  = 131072;                             // float[NA]
static constexpr size_t OFF_STOK = 262144;                             // int[ED*CAP]
static constexpr size_t OFF_ASLOT= 425984;                             // int[NA] (slot per assignment, -1 dropped)
static constexpr size_t OFF_W2T  = 1u << 20;                           // bf16[ED][HD][FD]
static constexpr size_t OFF_H    = OFF_W2T + (size_t)ED*HD*FD*2;       // bf16[ED][CAP][FD]
static constexpr size_t OFF_W1T  = OFF_H   + (size_t)ED*CAP*FD*2;      // bf16[ED][FD][HD]
static constexpr size_t OFF_XBF  = OFF_W1T + (size_t)ED*FD*HD*2;       // bf16[NTOK][HD]
static constexpr size_t OFF_EOUT = OFF_XBF + (size_t)NTOK*HD*2;        // fp16[ED][CAP][HD]

__device__ __forceinline__ unsigned short f2bf(float f) {
    __bf16 b = (__bf16)f;
    return __builtin_bit_cast(unsigned short, b);
}
__device__ __forceinline__ unsigned short f2h(float f) {
    _Float16 h = (_Float16)f;
    return __builtin_bit_cast(unsigned short, h);
}
__device__ __forceinline__ float h2f(unsigned short u) {
    return (float)__builtin_bit_cast(_Float16, u);
}

// gelu(tanh approx) == v * sigmoid(2*0.79788456*(v + 0.044715 v^3))  (exact identity)
__device__ __forceinline__ float gelu_fast(float v) {
    const float u = 1.5957691216057308f * (v + 0.044715f * v * v * v);
    return v / (1.f + __expf(-u));
}

// Direct global->LDS DMA, 16B per lane. LDS dest is wave-uniform base +
// lane*16 (HW semantics, m104/m108); global src is per-lane.
__device__ __forceinline__ void gl16(const unsigned short* g, unsigned short* l) {
    __builtin_amdgcn_global_load_lds(
        (const __attribute__((address_space(1))) unsigned int*)(const void*)g,
        (__attribute__((address_space(3))) unsigned int*)(void*)l, 16, 0, 0);
}

// ---------------------------------------------------------------------------
// in: [R][C] fp32 (per expert)  ->  out: [C][R] bf16 (per expert)
// ---------------------------------------------------------------------------
__global__ __launch_bounds__(256) void transpose_cast_kernel(
    const float* __restrict__ in, unsigned short* __restrict__ out, int R, int C)
{
    __shared__ unsigned short tile[32][33];
    const int e = blockIdx.z;
    in  += (size_t)e * R * C;
    out += (size_t)e * R * C;
    const int r0 = blockIdx.y * 32, c0 = blockIdx.x * 32;
    const int tr = threadIdx.x >> 3, tc = (threadIdx.x & 7) * 4;
    const float4 v = *(const float4*)(in + (size_t)(r0 + tr) * C + c0 + tc);
    tile[tr][tc + 0] = f2bf(v.x);
    tile[tr][tc + 1] = f2bf(v.y);
    tile[tr][tc + 2] = f2bf(v.z);
    tile[tr][tc + 3] = f2bf(v.w);
    __syncthreads();
    ushort4 o;
    o.x = tile[tc + 0][tr]; o.y = tile[tc + 1][tr];
    o.z = tile[tc + 2][tr]; o.w = tile[tc + 3][tr];
    *(ushort4*)(out + (size_t)(c0 + tr) * R + r0 + tc) = o;
}

// ---------------------------------------------------------------------------
// Router (+ fused x->bf16 cast): logits = x @ router_w (fp32), top-2, softmax.
// ---------------------------------------------------------------------------
__global__ __launch_bounds__(256) void router_kernel(
    const float* __restrict__ x, const float* __restrict__ rw,
    int* __restrict__ eidx, float* __restrict__ wgt,
    unsigned short* __restrict__ xbf)
{
    __shared__ float rws[HD * ED];
    const int tid = threadIdx.x;
    for (int i = tid * 4; i < HD * ED; i += 256 * 4)
        *(float4*)(rws + i) = *(const float4*)(rw + i);
    __syncthreads();

    const int wid = tid >> 6, lane = tid & 63;
    const int t = blockIdx.x * 4 + wid;
    const float* xr = x + (size_t)t * HD;

    float acc[ED];
#pragma unroll
    for (int e = 0; e < ED; e++) acc[e] = 0.f;

    float4 xv0 = *(const float4*)(xr + lane * 8);
    float4 xv1 = *(const float4*)(xr + lane * 8 + 4);
    float xv[8] = {xv0.x, xv0.y, xv0.z, xv0.w, xv1.x, xv1.y, xv1.z, xv1.w};

    union { unsigned short us[8]; uint4 v; } pk;
#pragma unroll
    for (int j = 0; j < 8; j++) pk.us[j] = f2bf(xv[j]);
    *(uint4*)(xbf + (size_t)t * HD + lane * 8) = pk.v;

#pragma unroll
    for (int j = 0; j < 8; j++) {
        const int h = lane * 8 + j;
#pragma unroll
        for (int e = 0; e < ED; e++) acc[e] += xv[j] * rws[h * ED + e];
    }
#pragma unroll
    for (int off = 32; off >= 1; off >>= 1) {
#pragma unroll
        for (int e = 0; e < ED; e++) acc[e] += __shfl_down(acc[e], off);
    }
    if (lane == 0) {
        int e0 = 0; float l0 = acc[0];
        for (int e = 1; e < ED; e++) if (acc[e] > l0) { l0 = acc[e]; e0 = e; }
        int e1 = 0; float l1 = -1e30f;
        for (int e = 0; e < ED; e++) {
            if (e == e0) continue;
            if (acc[e] > l1) { l1 = acc[e]; e1 = e; }
        }
        const float ex = expf(l1 - l0);
        const float inv = 1.f / (1.f + ex);
        eidx[t * 2 + 0] = e0;  eidx[t * 2 + 1] = e1;
        wgt [t * 2 + 0] = inv; wgt [t * 2 + 1] = ex * inv;
    }
}

// ---------------------------------------------------------------------------
// Deterministic slot assignment (stable-sort-by-expert semantics).
// Emits stok (slot -> token, for GEMM1 gather) and aslot (assignment -> slot,
// for the combine kernel; -1 = dropped).
// ---------------------------------------------------------------------------
__global__ __launch_bounds__(1024) void scan_kernel(
    const int* __restrict__ eidx,
    int* __restrict__ stok, int* __restrict__ aslot)
{
    __shared__ int running[ED];
    __shared__ int wcnt[16][ED];
    const int tid = threadIdx.x;

    for (int i = tid; i < ED * CAP; i += 1024) stok[i] = -1;
    if (tid < ED) running[tid] = 0;
    __syncthreads();

    const int lane = tid & 63, wid = tid >> 6;
    const unsigned long long below = (1ull << lane) - 1ull;

    for (int c = 0; c < NA / 1024; c++) {
        const int a = c * 1024 + tid;
        const int e = eidx[a];
        int myrank = 0;
#pragma unroll
        for (int ee = 0; ee < ED; ee++) {
            unsigned long long m = __ballot(e == ee);
            if (ee == e) myrank = __popcll(m & below);
            if (lane == 0) wcnt[wid][ee] = __popcll(m);
        }
        __syncthreads();
        int woff = 0;
        for (int ww = 0; ww < wid; ww++) woff += wcnt[ww][e];
        const int slot = running[e] + woff + myrank;
        if (slot < CAP) {
            stok[e * CAP + slot] = a >> 1;   // token = a / K
            aslot[a] = slot;
        } else {
            aslot[a] = -1;                   // dropped
        }
        __syncthreads();
        if (tid < ED) {
            int tot = 0;
            for (int ww = 0; ww < 16; ww++) tot += wcnt[ww][tid];
            running[tid] += tot;
        }
        __syncthreads();
    }
}

// ---------------------------------------------------------------------------
// MFMA GEMM, m97-structure: global_load_lds DMA staging (no VGPR round-trip,
// no ds_write port pressure), linear [2][128][32] LDS per operand (32 KB),
// ONE barrier per K-step, 2-step-unrolled so buffer indices are compile-time.
// Bank-conflict fix: source-side XOR swizzle (m173 pattern) — LDS chunk c of
// row R holds global chunk c ^ ((R>>1)&3); fragment reads apply the same XOR.
// Read conflicts drop to 2-way (free, m136); DMA writes are linear (0-way).
// NOTE (R1 post-mortem): do NOT set a min-waves floor in __launch_bounds__ —
// acc[4][4] needs 64 unified regs; a 5-waves/EU floor forced VGPR_Count=48
// and spilled the accumulators (WRITE_SIZE 64->663 MB of scratch traffic).
// Mapping: id%8 == expert == XCD; n fastest so gathered A rows land in L2
// once and get reused by all n-tiles; expert weight slab L2-resident.
// G1=true : hout = gelu(gather(x) @ B + bias)  [bf16]
// G1=false: hout = A @ B + bias                [fp16] (combined later)
// ---------------------------------------------------------------------------
template<int KD, int ND, int NT, bool G1>
__global__ __launch_bounds__(256) void gemm_mfma(
    const unsigned short* __restrict__ Abase,
    const unsigned short* __restrict__ Bt,
    const float* __restrict__ bias,
    const int* __restrict__ stok,
    unsigned short* __restrict__ hout)
{
    constexpr int BUFE = 128 * 32;            // 4096 elems = 8 KB per buf
    __shared__ __align__(16) unsigned short As[2 * BUFE];
    __shared__ __align__(16) unsigned short Bs[2 * BUFE];

    const int tid = threadIdx.x;
    const int e  = blockIdx.x & 7;            // expert == XCD (id%8 round-robin)
    const int g  = blockIdx.x >> 3;
    const int n0 = (g % NT) * 128;            // n fastest: reuse gathered A in L2
    const int m0 = (g / NT) * 128;

    const int lane = tid & 63;
    const int wid  = tid >> 6;

    // Staging map: wave w, instr p covers rows [(2w+p)*16, +16); lane ->
    // (row sub = lane>>2, chunk = lane&3). Global source chunk is XOR-swizzled.
    const int rsub = lane >> 2;                       // 0..15
    const int csw  = (lane & 3) ^ ((rsub >> 1) & 3);  // pre-swizzled src chunk

    const unsigned short *ag0, *ag1, *bg0, *bg1;
    {
        const int R0 = (wid * 2 + 0) * 16 + rsub;
        const int R1 = (wid * 2 + 1) * 16 + rsub;
        size_t a0, a1;
        if constexpr (G1) {
            const int t0 = stok[e * CAP + m0 + R0];
            const int t1 = stok[e * CAP + m0 + R1];
            a0 = (size_t)(t0 >= 0 ? t0 : 0);   // dropped -> row 0 (never read back)
            a1 = (size_t)(t1 >= 0 ? t1 : 0);
        } else {
            a0 = (size_t)(e * CAP + m0 + R0);
            a1 = (size_t)(e * CAP + m0 + R1);
        }
        ag0 = Abase + a0 * KD + csw * 8;
        ag1 = Abase + a1 * KD + csw * 8;
        bg0 = Bt + ((size_t)e * ND + n0 + R0) * KD + csw * 8;
        bg1 = Bt + ((size_t)e * ND + n0 + R1) * KD + csw * 8;
    }
    unsigned short* lA = As + (wid * 2) * 512;  // wave-uniform DMA dest bases
    unsigned short* lB = Bs + (wid * 2) * 512;

    const int wrow = (wid & 1) * 64;
    const int wcol = (wid >> 1) * 64;
    const int l15  = lane & 15;
    const int quad = lane >> 4;
    const int xq   = quad ^ ((l15 >> 1) & 3);   // read-side XOR (row>>1 & 3 == l15>>1 & 3)
    const int fA   = (wrow + l15) * 32 + xq * 8;
    const int fB   = (wcol + l15) * 32 + xq * 8;

    f32x4 acc[4][4];
#pragma unroll
    for (int i = 0; i < 4; i++)
#pragma unroll
        for (int j = 0; j < 4; j++) acc[i][j] = (f32x4)0.f;

#define STAGE(B, KC)                                                           \
    {                                                                          \
        gl16(ag0 + (KC), lA + (B) * BUFE);                                     \
        gl16(ag1 + (KC), lA + (B) * BUFE + 512);                               \
        gl16(bg0 + (KC), lB + (B) * BUFE);                                     \
        gl16(bg1 + (KC), lB + (B) * BUFE + 512);                               \
    }

#define COMPUTE(B)                                                             \
    {                                                                          \
        const unsigned short* Ab = As + (B) * BUFE;                            \
        const unsigned short* Bb = Bs + (B) * BUFE;                            \
        bf16x8 af[4], bfv[4];                                                  \
        _Pragma("unroll")                                                      \
        for (int i = 0; i < 4; i++) af[i]  = *(const bf16x8*)(Ab + fA + i * 512); \
        _Pragma("unroll")                                                      \
        for (int j = 0; j < 4; j++) bfv[j] = *(const bf16x8*)(Bb + fB + j * 512); \
        _Pragma("unroll")                                                      \
        for (int i = 0; i < 4; i++)                                            \
            _Pragma("unroll")                                                  \
            for (int j = 0; j < 4; j++)                                        \
                acc[i][j] = __builtin_amdgcn_mfma_f32_16x16x32_bf16(           \
                    af[i], bfv[j], acc[i][j], 0, 0, 0);                        \
    }

    // Prologue: DMA tile 0 into buf0; barrier drains vmcnt -> buf0 ready.
    STAGE(0, 0);
    __syncthreads();

    // Steady state: issue next tile's DMA first (hides under MFMA), compute
    // current, then one barrier (compiler emits the vmcnt/lgkm drain there).
    for (int kc = 0; kc <= KD - 128; kc += 64) {
        STAGE(1, kc + 32);
        COMPUTE(0);
        __syncthreads();
        STAGE(0, kc + 64);
        COMPUTE(1);
        __syncthreads();
    }
    STAGE(1, KD - 32);
    COMPUTE(0);
    __syncthreads();
    COMPUTE(1);
#undef STAGE
#undef COMPUTE

    // Epilogue. C/D layout: col = lane&15, row = quad*4 + reg.
#pragma unroll
    for (int i = 0; i < 4; i++) {
#pragma unroll
        for (int g2 = 0; g2 < 4; g2++) {
            const int m = wrow + i * 16 + quad * 4 + g2;
            unsigned short* hrow = hout + ((size_t)e * CAP + m0 + m) * ND + n0;
#pragma unroll
            for (int j = 0; j < 4; j++) {
                const int n = wcol + j * 16 + l15;
                const float v = acc[i][j][g2] + bias[(size_t)e * ND + n0 + n];
                hrow[n] = G1 ? f2bf(gelu_fast(v)) : f2h(v);
            }
        }
    }
}

// ---------------------------------------------------------------------------
// Combine: out[t] = sum_k wgt[t,k] * eout[eidx[t,k], aslot[t,k]]  (no atomics,
// fully coalesced; writes every output element so no memset needed).
// ---------------------------------------------------------------------------
__global__ __launch_bounds__(256) void combine_kernel(
    const unsigned short* __restrict__ eout,
    const int* __restrict__ eidx, const int* __restrict__ aslot,
    const float* __restrict__ wgt, float* __restrict__ out)
{
    const int tid = threadIdx.x;
    const int t  = blockIdx.x * 2 + (tid >> 7);   // 128 threads per token
    const int h0 = (tid & 127) * 4;
    float r0 = 0.f, r1 = 0.f, r2 = 0.f, r3 = 0.f;
#pragma unroll
    for (int k = 0; k < 2; k++) {
        const int a = t * 2 + k;
        const int s = aslot[a];
        if (s >= 0) {
            const float w = wgt[a];
            const int e = eidx[a];
            const ushort4 v = *(const ushort4*)(eout + ((size_t)e * CAP + s) * HD + h0);
            r0 += w * h2f(v.x); r1 += w * h2f(v.y);
            r2 += w * h2f(v.z); r3 += w * h2f(v.w);
        }
    }
    float4 o; o.x = r0; o.y = r1; o.z = r2; o.w = r3;
    *(float4*)(out + (size_t)t * HD + h0) = o;
}

extern "C" void kernel_launch(void* const* d_in, const int* in_sizes, int n_in,
                              void* d_out, int out_size, void* d_ws, size_t ws_size,
                              hipStream_t stream)
{
    const float* x  = (const float*)d_in[0];
    const float* rw = (const float*)d_in[1];
    const float* w1 = (const float*)d_in[2];
    const float* b1 = (const float*)d_in[3];
    const float* w2 = (const float*)d_in[4];
    const float* b2 = (const float*)d_in[5];
    float* out = (float*)d_out;

    char* ws = (char*)d_ws;
    int*   eidx  = (int*)  (ws + OFF_EIDX);
    float* wgt   = (float*)(ws + OFF_WGT);
    int*   stok  = (int*)  (ws + OFF_STOK);
    int*   aslot = (int*)  (ws + OFF_ASLOT);
    unsigned short* w2t  = (unsigned short*)(ws + OFF_W2T);
    unsigned short* hbuf = (unsigned short*)(ws + OFF_H);
    unsigned short* w1t  = (unsigned short*)(ws + OFF_W1T);
    unsigned short* xbf  = (unsigned short*)(ws + OFF_XBF);
    unsigned short* eout = (unsigned short*)(ws + OFF_EOUT);

    transpose_cast_kernel<<<dim3(FD / 32, HD / 32, ED), 256, 0, stream>>>(w1, w1t, HD, FD);
    transpose_cast_kernel<<<dim3(HD / 32, FD / 32, ED), 256, 0, stream>>>(w2, w2t, FD, HD);
    router_kernel<<<NTOK / 4, 256, 0, stream>>>(x, rw, eidx, wgt, xbf);
    scan_kernel<<<1, 1024, 0, stream>>>(eidx, stok, aslot);

    // GEMM1: h = gelu(gather(x) @ w1 + b1)  [bf16]
    gemm_mfma<HD, FD, FD/128, true>
        <<<8 * (FD/128) * (CAP/128), 256, 0, stream>>>(
        xbf, w1t, b1, stok, hbuf);

    // GEMM2: eout = h @ w2 + b2  [fp16, per-slot]
    gemm_mfma<FD, HD, HD/128, false>
        <<<8 * (HD/128) * (CAP/128), 256, 0, stream>>>(
        hbuf, w2t, b2, nullptr, eout);

    // Weighted scatter-free combine (writes all tokens; replaces memset+atomics)
    combine_kernel<<<NTOK / 2, 256, 0, stream>>>(eout, eidx, aslot, wgt, out);
}

// Round 4
// 464.581 us; speedup vs baseline: 1.5377x; 1.1332x over previous
//
#include <hip/hip_runtime.h>
#include <hip/hip_bf16.h>

// Problem constants (static per reference)
#define NTOK 16384   // B*T
#define HD   512     // H
#define ED   8       // E experts
#define FD   2048    // F
#define CAP  5120    // capacity per expert
#define NA   32768   // NTOK * K(=2)

typedef __bf16 bf16x8 __attribute__((ext_vector_type(8)));
typedef float  f32x4  __attribute__((ext_vector_type(4)));

// Workspace layout (bytes). Total ~249 MB.
static constexpr size_t OFF_EIDX = 0;                                  // int[NA]
static constexpr size_t OFF_WGT  = 131072;                             // float[NA]
static constexpr size_t OFF_STOK = 262144;                             // int[ED*CAP]
static constexpr size_t OFF_ASLOT= 425984;                             // int[NA] (slot per assignment, -1 dropped)
static constexpr size_t OFF_ECNT = 557056;                             // int[ED] (clipped expert counts)
static constexpr size_t OFF_W2T  = 1u << 20;                           // bf16[ED][HD][FD]
static constexpr size_t OFF_H    = OFF_W2T + (size_t)ED*HD*FD*2;       // bf16[ED][CAP][FD]
static constexpr size_t OFF_W1T  = OFF_H   + (size_t)ED*CAP*FD*2;      // bf16[ED][FD][HD]
static constexpr size_t OFF_XBF  = OFF_W1T + (size_t)ED*FD*HD*2;       // bf16[NTOK][HD]
static constexpr size_t OFF_EOUT = OFF_XBF + (size_t)NTOK*HD*2;        // fp16[ED][CAP][HD]

__device__ __forceinline__ unsigned short f2bf(float f) {
    __bf16 b = (__bf16)f;
    return __builtin_bit_cast(unsigned short, b);
}
__device__ __forceinline__ unsigned short f2h(float f) {
    _Float16 h = (_Float16)f;
    return __builtin_bit_cast(unsigned short, h);
}
__device__ __forceinline__ float h2f(unsigned short u) {
    return (float)__builtin_bit_cast(_Float16, u);
}

// gelu(tanh approx) == v * sigmoid(2*0.79788456*(v + 0.044715 v^3))  (exact identity)
// v_rcp_f32 (~1ulp) instead of the exact-div sequence: invisible after bf16
// rounding, saves ~7 VALU insts per element (R2: epilogue VALU was 56% busy).
__device__ __forceinline__ float gelu_fast(float v) {
    const float t = v * v;
    const float u = v * fmaf(t, 0.0713548214f, 1.5957691216f);
    const float e = __expf(-u);
    return v * __builtin_amdgcn_rcpf(1.f + e);
}

// Direct global->LDS DMA, 16B per lane. LDS dest is wave-uniform base +
// lane*16 (HW semantics, m104/m108); global src is per-lane.
__device__ __forceinline__ void gl16(const unsigned short* g, unsigned short* l) {
    __builtin_amdgcn_global_load_lds(
        (const __attribute__((address_space(1))) unsigned int*)(const void*)g,
        (__attribute__((address_space(3))) unsigned int*)(void*)l, 16, 0, 0);
}

// ---------------------------------------------------------------------------
// in: [R][C] fp32 (per expert)  ->  out: [C][R] bf16 (per expert)
// ---------------------------------------------------------------------------
__global__ __launch_bounds__(256) void transpose_cast_kernel(
    const float* __restrict__ in, unsigned short* __restrict__ out, int R, int C)
{
    __shared__ unsigned short tile[32][33];
    const int e = blockIdx.z;
    in  += (size_t)e * R * C;
    out += (size_t)e * R * C;
    const int r0 = blockIdx.y * 32, c0 = blockIdx.x * 32;
    const int tr = threadIdx.x >> 3, tc = (threadIdx.x & 7) * 4;
    const float4 v = *(const float4*)(in + (size_t)(r0 + tr) * C + c0 + tc);
    tile[tr][tc + 0] = f2bf(v.x);
    tile[tr][tc + 1] = f2bf(v.y);
    tile[tr][tc + 2] = f2bf(v.z);
    tile[tr][tc + 3] = f2bf(v.w);
    __syncthreads();
    ushort4 o;
    o.x = tile[tc + 0][tr]; o.y = tile[tc + 1][tr];
    o.z = tile[tc + 2][tr]; o.w = tile[tc + 3][tr];
    *(ushort4*)(out + (size_t)(c0 + tr) * R + r0 + tc) = o;
}

// ---------------------------------------------------------------------------
// Router (+ fused x->bf16 cast): logits = x @ router_w (fp32), top-2, softmax.
// ---------------------------------------------------------------------------
__global__ __launch_bounds__(256) void router_kernel(
    const float* __restrict__ x, const float* __restrict__ rw,
    int* __restrict__ eidx, float* __restrict__ wgt,
    unsigned short* __restrict__ xbf)
{
    __shared__ float rws[HD * ED];
    const int tid = threadIdx.x;
    for (int i = tid * 4; i < HD * ED; i += 256 * 4)
        *(float4*)(rws + i) = *(const float4*)(rw + i);
    __syncthreads();

    const int wid = tid >> 6, lane = tid & 63;
    const int t = blockIdx.x * 4 + wid;
    const float* xr = x + (size_t)t * HD;

    float acc[ED];
#pragma unroll
    for (int e = 0; e < ED; e++) acc[e] = 0.f;

    float4 xv0 = *(const float4*)(xr + lane * 8);
    float4 xv1 = *(const float4*)(xr + lane * 8 + 4);
    float xv[8] = {xv0.x, xv0.y, xv0.z, xv0.w, xv1.x, xv1.y, xv1.z, xv1.w};

    union { unsigned short us[8]; uint4 v; } pk;
#pragma unroll
    for (int j = 0; j < 8; j++) pk.us[j] = f2bf(xv[j]);
    *(uint4*)(xbf + (size_t)t * HD + lane * 8) = pk.v;

#pragma unroll
    for (int j = 0; j < 8; j++) {
        const int h = lane * 8 + j;
#pragma unroll
        for (int e = 0; e < ED; e++) acc[e] += xv[j] * rws[h * ED + e];
    }
#pragma unroll
    for (int off = 32; off >= 1; off >>= 1) {
#pragma unroll
        for (int e = 0; e < ED; e++) acc[e] += __shfl_down(acc[e], off);
    }
    if (lane == 0) {
        int e0 = 0; float l0 = acc[0];
        for (int e = 1; e < ED; e++) if (acc[e] > l0) { l0 = acc[e]; e0 = e; }
        int e1 = 0; float l1 = -1e30f;
        for (int e = 0; e < ED; e++) {
            if (e == e0) continue;
            if (acc[e] > l1) { l1 = acc[e]; e1 = e; }
        }
        const float ex = expf(l1 - l0);
        const float inv = 1.f / (1.f + ex);
        eidx[t * 2 + 0] = e0;  eidx[t * 2 + 1] = e1;
        wgt [t * 2 + 0] = inv; wgt [t * 2 + 1] = ex * inv;
    }
}

// ---------------------------------------------------------------------------
// Deterministic slot assignment (stable-sort-by-expert semantics).
// Emits stok (slot -> token), aslot (assignment -> slot, -1 = dropped), and
// ecnt (clipped per-expert count, for GEMM tile early-exit).
// ---------------------------------------------------------------------------
__global__ __launch_bounds__(1024) void scan_kernel(
    const int* __restrict__ eidx,
    int* __restrict__ stok, int* __restrict__ aslot, int* __restrict__ ecnt)
{
    __shared__ int running[ED];
    __shared__ int wcnt[16][ED];
    const int tid = threadIdx.x;

    for (int i = tid; i < ED * CAP; i += 1024) stok[i] = -1;
    if (tid < ED) running[tid] = 0;
    __syncthreads();

    const int lane = tid & 63, wid = tid >> 6;
    const unsigned long long below = (1ull << lane) - 1ull;

    for (int c = 0; c < NA / 1024; c++) {
        const int a = c * 1024 + tid;
        const int e = eidx[a];
        int myrank = 0;
#pragma unroll
        for (int ee = 0; ee < ED; ee++) {
            unsigned long long m = __ballot(e == ee);
            if (ee == e) myrank = __popcll(m & below);
            if (lane == 0) wcnt[wid][ee] = __popcll(m);
        }
        __syncthreads();
        int woff = 0;
        for (int ww = 0; ww < wid; ww++) woff += wcnt[ww][e];
        const int slot = running[e] + woff + myrank;
        if (slot < CAP) {
            stok[e * CAP + slot] = a >> 1;   // token = a / K
            aslot[a] = slot;
        } else {
            aslot[a] = -1;                   // dropped
        }
        __syncthreads();
        if (tid < ED) {
            int tot = 0;
            for (int ww = 0; ww < 16; ww++) tot += wcnt[ww][tid];
            running[tid] += tot;
        }
        __syncthreads();
    }
    if (tid < ED) ecnt[tid] = running[tid] < CAP ? running[tid] : CAP;
}

// ---------------------------------------------------------------------------
// MFMA GEMM, m97-structure: global_load_lds DMA staging, linear [2][128][32]
// LDS per operand (32 KB), ONE barrier per K-step, 2-step-unrolled.
// Bank-conflict fix: source-side XOR swizzle (m173) — verified 0 conflicts.
// R3 changes:
//  * early-exit tiles beyond ecnt[e] (~18% of tiles are capacity padding);
//  * MFMA operands SWAPPED (mfma(bfv, af)): D col=lane&15 -> m, row -> n, so
//    each thread holds 4 consecutive n per subtile -> ushort4 stores (16 VMEM
//    insts/thread instead of 64 scalar) and float4 bias loads;
//  * gelu uses v_rcp_f32 (R2 post-mortem: exact-div epilogue = VALUBusy 56%).
// NOTE (R1 post-mortem): no min-waves floor in __launch_bounds__ — acc[4][4]
// needs 64 unified regs; a floor of 5 spilled accumulators to scratch.
// G1=true : hout = gelu(gather(x) @ B + bias)  [bf16]
// G1=false: hout = A @ B + bias                [fp16] (combined later)
// ---------------------------------------------------------------------------
template<int KD, int ND, int NT, bool G1>
__global__ __launch_bounds__(256) void gemm_mfma(
    const unsigned short* __restrict__ Abase,
    const unsigned short* __restrict__ Bt,
    const float* __restrict__ bias,
    const int* __restrict__ stok,
    const int* __restrict__ ecnt,
    unsigned short* __restrict__ hout)
{
    constexpr int BUFE = 128 * 32;            // 4096 elems = 8 KB per buf
    __shared__ __align__(16) unsigned short As[2 * BUFE];
    __shared__ __align__(16) unsigned short Bs[2 * BUFE];

    const int tid = threadIdx.x;
    const int e  = blockIdx.x & 7;            // expert == XCD (id%8 round-robin)
    const int g  = blockIdx.x >> 3;
    const int n0 = (g % NT) * 128;            // n fastest: reuse gathered A in L2
    const int m0 = (g / NT) * 128;

    if (m0 >= ecnt[e]) return;                // capacity-padding tile: skip

    const int lane = tid & 63;
    const int wid  = tid >> 6;

    // Staging map: wave w, instr p covers rows [(2w+p)*16, +16); lane ->
    // (row sub = lane>>2, chunk = lane&3). Global source chunk is XOR-swizzled.
    const int rsub = lane >> 2;                       // 0..15
    const int csw  = (lane & 3) ^ ((rsub >> 1) & 3);  // pre-swizzled src chunk

    const unsigned short *ag0, *ag1, *bg0, *bg1;
    {
        const int R0 = (wid * 2 + 0) * 16 + rsub;
        const int R1 = (wid * 2 + 1) * 16 + rsub;
        size_t a0, a1;
        if constexpr (G1) {
            const int t0 = stok[e * CAP + m0 + R0];
            const int t1 = stok[e * CAP + m0 + R1];
            a0 = (size_t)(t0 >= 0 ? t0 : 0);   // dropped -> row 0 (never read back)
            a1 = (size_t)(t1 >= 0 ? t1 : 0);
        } else {
            a0 = (size_t)(e * CAP + m0 + R0);
            a1 = (size_t)(e * CAP + m0 + R1);
        }
        ag0 = Abase + a0 * KD + csw * 8;
        ag1 = Abase + a1 * KD + csw * 8;
        bg0 = Bt + ((size_t)e * ND + n0 + R0) * KD + csw * 8;
        bg1 = Bt + ((size_t)e * ND + n0 + R1) * KD + csw * 8;
    }
    unsigned short* lA = As + (wid * 2) * 512;  // wave-uniform DMA dest bases
    unsigned short* lB = Bs + (wid * 2) * 512;

    const int wrow = (wid & 1) * 64;
    const int wcol = (wid >> 1) * 64;
    const int l15  = lane & 15;
    const int quad = lane >> 4;
    const int xq   = quad ^ ((l15 >> 1) & 3);   // read-side XOR (row>>1 & 3 == l15>>1 & 3)
    const int fA   = (wrow + l15) * 32 + xq * 8;
    const int fB   = (wcol + l15) * 32 + xq * 8;

    f32x4 acc[4][4];
#pragma unroll
    for (int i = 0; i < 4; i++)
#pragma unroll
        for (int j = 0; j < 4; j++) acc[i][j] = (f32x4)0.f;

#define STAGE(B, KC)                                                           \
    {                                                                          \
        gl16(ag0 + (KC), lA + (B) * BUFE);                                     \
        gl16(ag1 + (KC), lA + (B) * BUFE + 512);                               \
        gl16(bg0 + (KC), lB + (B) * BUFE);                                     \
        gl16(bg1 + (KC), lB + (B) * BUFE + 512);                               \
    }

// Swapped-operand MFMA: D = bfv x af -> col(lane&15) indexes m, row indexes n.
#define COMPUTE(B)                                                             \
    {                                                                          \
        const unsigned short* Ab = As + (B) * BUFE;                            \
        const unsigned short* Bb = Bs + (B) * BUFE;                            \
        bf16x8 af[4], bfv[4];                                                  \
        _Pragma("unroll")                                                      \
        for (int i = 0; i < 4; i++) af[i]  = *(const bf16x8*)(Ab + fA + i * 512); \
        _Pragma("unroll")                                                      \
        for (int j = 0; j < 4; j++) bfv[j] = *(const bf16x8*)(Bb + fB + j * 512); \
        _Pragma("unroll")                                                      \
        for (int i = 0; i < 4; i++)                                            \
            _Pragma("unroll")                                                  \
            for (int j = 0; j < 4; j++)                                        \
                acc[i][j] = __builtin_amdgcn_mfma_f32_16x16x32_bf16(           \
                    bfv[j], af[i], acc[i][j], 0, 0, 0);                        \
    }

    // Prologue: DMA tile 0 into buf0; barrier drains vmcnt -> buf0 ready.
    STAGE(0, 0);
    __syncthreads();

    // Steady state: issue next tile's DMA first (hides under MFMA), compute
    // current, then one barrier (compiler emits the vmcnt/lgkm drain there).
    for (int kc = 0; kc <= KD - 128; kc += 64) {
        STAGE(1, kc + 32);
        COMPUTE(0);
        __syncthreads();
        STAGE(0, kc + 64);
        COMPUTE(1);
        __syncthreads();
    }
    STAGE(1, KD - 32);
    COMPUTE(0);
    __syncthreads();
    COMPUTE(1);
#undef STAGE
#undef COMPUTE

    // Epilogue (transposed D): m = wrow + i*16 + l15, n = wcol + j*16 + quad*4
    // + g2 -> 4 consecutive n per (i,j) -> one ushort4 store each.
#pragma unroll
    for (int i = 0; i < 4; i++) {
        unsigned short* hrow = hout
            + ((size_t)e * CAP + m0 + wrow + i * 16 + l15) * ND
            + n0 + wcol + quad * 4;
#pragma unroll
        for (int j = 0; j < 4; j++) {
            const float4 b4 = *(const float4*)(
                bias + (size_t)e * ND + n0 + wcol + j * 16 + quad * 4);
            const float v0 = acc[i][j][0] + b4.x;
            const float v1 = acc[i][j][1] + b4.y;
            const float v2 = acc[i][j][2] + b4.z;
            const float v3 = acc[i][j][3] + b4.w;
            ushort4 o;
            if constexpr (G1) {
                o.x = f2bf(gelu_fast(v0)); o.y = f2bf(gelu_fast(v1));
                o.z = f2bf(gelu_fast(v2)); o.w = f2bf(gelu_fast(v3));
            } else {
                o.x = f2h(v0); o.y = f2h(v1); o.z = f2h(v2); o.w = f2h(v3);
            }
            *(ushort4*)(hrow + j * 16) = o;
        }
    }
}

// ---------------------------------------------------------------------------
// Combine: out[t] = sum_k wgt[t,k] * eout[eidx[t,k], aslot[t,k]]  (no atomics,
// fully coalesced; writes every output element so no memset needed).
// ---------------------------------------------------------------------------
__global__ __launch_bounds__(256) void combine_kernel(
    const unsigned short* __restrict__ eout,
    const int* __restrict__ eidx, const int* __restrict__ aslot,
    const float* __restrict__ wgt, float* __restrict__ out)
{
    const int tid = threadIdx.x;
    const int t  = blockIdx.x * 2 + (tid >> 7);   // 128 threads per token
    const int h0 = (tid & 127) * 4;
    float r0 = 0.f, r1 = 0.f, r2 = 0.f, r3 = 0.f;
#pragma unroll
    for (int k = 0; k < 2; k++) {
        const int a = t * 2 + k;
        const int s = aslot[a];
        if (s >= 0) {
            const float w = wgt[a];
            const int e = eidx[a];
            const ushort4 v = *(const ushort4*)(eout + ((size_t)e * CAP + s) * HD + h0);
            r0 += w * h2f(v.x); r1 += w * h2f(v.y);
            r2 += w * h2f(v.z); r3 += w * h2f(v.w);
        }
    }
    float4 o; o.x = r0; o.y = r1; o.z = r2; o.w = r3;
    *(float4*)(out + (size_t)t * HD + h0) = o;
}

extern "C" void kernel_launch(void* const* d_in, const int* in_sizes, int n_in,
                              void* d_out, int out_size, void* d_ws, size_t ws_size,
                              hipStream_t stream)
{
    const float* x  = (const float*)d_in[0];
    const float* rw = (const float*)d_in[1];
    const float* w1 = (const float*)d_in[2];
    const float* b1 = (const float*)d_in[3];
    const float* w2 = (const float*)d_in[4];
    const float* b2 = (const float*)d_in[5];
    float* out = (float*)d_out;

    char* ws = (char*)d_ws;
    int*   eidx  = (int*)  (ws + OFF_EIDX);
    float* wgt   = (float*)(ws + OFF_WGT);
    int*   stok  = (int*)  (ws + OFF_STOK);
    int*   aslot = (int*)  (ws + OFF_ASLOT);
    int*   ecnt  = (int*)  (ws + OFF_ECNT);
    unsigned short* w2t  = (unsigned short*)(ws + OFF_W2T);
    unsigned short* hbuf = (unsigned short*)(ws + OFF_H);
    unsigned short* w1t  = (unsigned short*)(ws + OFF_W1T);
    unsigned short* xbf  = (unsigned short*)(ws + OFF_XBF);
    unsigned short* eout = (unsigned short*)(ws + OFF_EOUT);

    transpose_cast_kernel<<<dim3(FD / 32, HD / 32, ED), 256, 0, stream>>>(w1, w1t, HD, FD);
    transpose_cast_kernel<<<dim3(HD / 32, FD / 32, ED), 256, 0, stream>>>(w2, w2t, FD, HD);
    router_kernel<<<NTOK / 4, 256, 0, stream>>>(x, rw, eidx, wgt, xbf);
    scan_kernel<<<1, 1024, 0, stream>>>(eidx, stok, aslot, ecnt);

    // GEMM1: h = gelu(gather(x) @ w1 + b1)  [bf16]
    gemm_mfma<HD, FD, FD/128, true>
        <<<8 * (FD/128) * (CAP/128), 256, 0, stream>>>(
        xbf, w1t, b1, stok, ecnt, hbuf);

    // GEMM2: eout = h @ w2 + b2  [fp16, per-slot]
    gemm_mfma<FD, HD, HD/128, false>
        <<<8 * (HD/128) * (CAP/128), 256, 0, stream>>>(
        hbuf, w2t, b2, nullptr, ecnt, eout);

    // Weighted scatter-free combine (writes all tokens; replaces memset+atomics)
    combine_kernel<<<NTOK / 2, 256, 0, stream>>>(eout, eidx, aslot, wgt, out);
}